// Round 12
// baseline (344.607 us; speedup 1.0000x reference)
//
#include <hip/hip_runtime.h>
#include <hip/hip_fp16.h>

// GDE func: out = MLP(relu(mean_agg(z,edges)@Wg + z@Ws + bg))
// Round 11 -> 12:
//  (1) T3 test at CORRECT regime: BK=32 double-buffered prefetch for the
//      512-col GEMMs at the SAME 48KB LDS footprint (3 blocks/CU kept).
//      R7/R8 prefetch nulls were at 1 block/CU where nothing overlaps.
//      gemm1/gemm4 stay on proven gemm_r -> within-run A/B vs gemm3.
//  (2) gather: masked 8-wide independent first batch (deg<=8 = common case
//      fully parallel); cast_z16 writes Xc z-half (gather sheds 51MB).

typedef _Float16 f16;
typedef __attribute__((ext_vector_type(4))) _Float16 f16x4;
typedef __attribute__((ext_vector_type(8))) _Float16 f16x8;
typedef __attribute__((ext_vector_type(4))) float f32x4;

__device__ __forceinline__ void async_load16(const void* g, void* lds) {
  __builtin_amdgcn_global_load_lds(
      (const __attribute__((address_space(1))) void*)g,
      (__attribute__((address_space(3))) void*)lds, 16, 0, 0);
}

#define VMBAR()                                         \
  do {                                                  \
    asm volatile("s_waitcnt vmcnt(0)" ::: "memory");    \
    __builtin_amdgcn_s_barrier();                       \
    __builtin_amdgcn_sched_barrier(0);                  \
  } while (0)

__device__ __forceinline__ float fast_tanh(float x) {
  float a = fabsf(x);
  float e = __expf(-2.0f * a);
  float r = (1.0f - e) * __builtin_amdgcn_rcpf(1.0f + e);
  return copysignf(r, x);
}

__global__ __launch_bounds__(256) void zero_kernel(int* __restrict__ p, int n) {
  int i = blockIdx.x * 256 + threadIdx.x;
  int stride = gridDim.x * 256;
  for (; i < n; i += stride) p[i] = 0;
}

// ---- CSR build ----
__global__ __launch_bounds__(256) void deg_count(const int* __restrict__ dst,
                                                 int* __restrict__ degi, int E) {
  int e = blockIdx.x * 256 + threadIdx.x;
  if (e < E) atomicAdd(&degi[dst[e]], 1);
}

__global__ __launch_bounds__(256) void scan_partial(const int* __restrict__ degi,
                                                    int* __restrict__ bsum, int N) {
  __shared__ int lds[256];
  int b = blockIdx.x, t = threadIdx.x;
  int s = 0;
#pragma unroll
  for (int j = 0; j < 4; ++j) {
    int idx = b * 1024 + t * 4 + j;
    if (idx < N) s += degi[idx];
  }
  lds[t] = s;
  __syncthreads();
  for (int off = 128; off > 0; off >>= 1) {
    if (t < off) lds[t] += lds[t + off];
    __syncthreads();
  }
  if (t == 0) bsum[b] = lds[0];
}

__global__ void scan_bsums(const int* __restrict__ bsum, int* __restrict__ boff,
                           int* __restrict__ row_start, int nb, int N) {
  if (threadIdx.x == 0 && blockIdx.x == 0) {
    int acc = 0;
    for (int i = 0; i < nb; ++i) { boff[i] = acc; acc += bsum[i]; }
    row_start[N] = acc;  // == E
  }
}

__global__ __launch_bounds__(256) void scan_final(
    const int* __restrict__ degi, const int* __restrict__ boff,
    int* __restrict__ row_start, int* __restrict__ cursor, int N) {
  __shared__ int lds[256];
  int b = blockIdx.x, t = threadIdx.x;
  int base = b * 1024;
  int v[4];
  int s = 0;
#pragma unroll
  for (int j = 0; j < 4; ++j) {
    int idx = base + t * 4 + j;
    v[j] = (idx < N) ? degi[idx] : 0;
    s += v[j];
  }
  lds[t] = s;
  __syncthreads();
  for (int off = 1; off < 256; off <<= 1) {
    int x = lds[t];
    int y = (t >= off) ? lds[t - off] : 0;
    __syncthreads();
    lds[t] = x + y;
    __syncthreads();
  }
  int pre = boff[b] + lds[t] - s;
#pragma unroll
  for (int j = 0; j < 4; ++j) {
    int idx = base + t * 4 + j;
    if (idx < N) { row_start[idx] = pre; cursor[idx] = pre; pre += v[j]; }
  }
}

__global__ __launch_bounds__(256) void fill_adj(const int* __restrict__ src,
                                                const int* __restrict__ dst,
                                                int* __restrict__ cursor,
                                                int* __restrict__ adj, int E) {
  int e = blockIdx.x * 256 + threadIdx.x;
  if (e >= E) return;
  int p = atomicAdd(&cursor[dst[e]], 1);
  adj[p] = src[e];
}

// ---- cast z -> f16 table AND write Xc's z-half directly ----
__global__ __launch_bounds__(256) void cast_z16(const float* __restrict__ z,
                                                f16* __restrict__ z16,
                                                f16* __restrict__ Xc, int n4) {
  int i = blockIdx.x * 256 + threadIdx.x;
  int stride = gridDim.x * 256;
  for (; i < n4; i += stride) {
    float4 v = *(const float4*)(z + 4 * (long long)i);
    f16x4 c;
    c[0] = (f16)v.x; c[1] = (f16)v.y; c[2] = (f16)v.z; c[3] = (f16)v.w;
    *(f16x4*)(z16 + 4 * (long long)i) = c;
    int node = i >> 5, sl = i & 31;
    *(f16x4*)(Xc + (long long)node * 256 + 128 + 4 * sl) = c;
  }
}

// ---- gather + mean -> Xc mean-half: 32 lanes/node, masked 8-wide batch ----
// adj is allocated with 8 pad ints so the masked batch never faults.
__global__ __launch_bounds__(256) void gather_xcat(
    const f16* __restrict__ z16, const int* __restrict__ row_start,
    const int* __restrict__ adj, f16* __restrict__ Xc, int N) {
  int node = (blockIdx.x * 256 + threadIdx.x) >> 5;
  if (node >= N) return;
  int lane = threadIdx.x & 31;
  int beg = row_start[node], end = row_start[node + 1];
  float a0 = 0, a1 = 0, a2 = 0, a3 = 0;
  // masked 8-wide independent batch (fully covers ~84% of nodes)
#pragma unroll
  for (int j = 0; j < 8; ++j) {
    int idx = beg + j;
    bool vld = idx < end;
    int nb = vld ? adj[idx] : node;  // adj read stays in padded array
    f16x4 x = *(const f16x4*)(z16 + (long long)nb * 128 + 4 * lane);
    float w = vld ? 1.0f : 0.0f;
    a0 += w * (float)x[0]; a1 += w * (float)x[1];
    a2 += w * (float)x[2]; a3 += w * (float)x[3];
  }
  int i = beg + 8;
  if (i < end) {
    float b0 = 0, b1 = 0, b2 = 0, b3 = 0;
    float c0 = 0, c1 = 0, c2 = 0, c3 = 0;
    float d0 = 0, d1 = 0, d2 = 0, d3 = 0;
    for (; i + 4 <= end; i += 4) {
      int n0 = adj[i], n1 = adj[i + 1], n2 = adj[i + 2], n3 = adj[i + 3];
      f16x4 v0 = *(const f16x4*)(z16 + (long long)n0 * 128 + 4 * lane);
      f16x4 v1 = *(const f16x4*)(z16 + (long long)n1 * 128 + 4 * lane);
      f16x4 v2 = *(const f16x4*)(z16 + (long long)n2 * 128 + 4 * lane);
      f16x4 v3 = *(const f16x4*)(z16 + (long long)n3 * 128 + 4 * lane);
      a0 += (float)v0[0]; a1 += (float)v0[1]; a2 += (float)v0[2]; a3 += (float)v0[3];
      b0 += (float)v1[0]; b1 += (float)v1[1]; b2 += (float)v1[2]; b3 += (float)v1[3];
      c0 += (float)v2[0]; c1 += (float)v2[1]; c2 += (float)v2[2]; c3 += (float)v2[3];
      d0 += (float)v3[0]; d1 += (float)v3[1]; d2 += (float)v3[2]; d3 += (float)v3[3];
    }
    for (; i < end; ++i) {
      f16x4 v = *(const f16x4*)(z16 + (long long)adj[i] * 128 + 4 * lane);
      a0 += (float)v[0]; a1 += (float)v[1]; a2 += (float)v[2]; a3 += (float)v[3];
    }
    a0 += b0 + c0 + d0; a1 += b1 + c1 + d1;
    a2 += b2 + c2 + d2; a3 += b3 + c3 + d3;
  }
  int dg = end - beg;
  float inv = 1.0f / (float)(dg > 1 ? dg : 1);
  long long o = (long long)node * 256;
  f16x4 m;
  m[0] = (f16)(a0 * inv); m[1] = (f16)(a1 * inv);
  m[2] = (f16)(a2 * inv); m[3] = (f16)(a3 * inv);
  *(f16x4*)(Xc + o + 4 * lane) = m;
}

// ---- merged weight prep (all Wt [col][K] f16) ----
__global__ __launch_bounds__(256) void prep_weights(
    const float* __restrict__ Wg, const float* __restrict__ Ws,
    const float* __restrict__ W1, const float* __restrict__ W2,
    const float* __restrict__ W3, f16* __restrict__ wgs, f16* __restrict__ wt1,
    f16* __restrict__ wt2, f16* __restrict__ wt3) {
  int i = blockIdx.x * 256 + threadIdx.x;
  int stride = gridDim.x * 256;
  for (; i < 425984; i += stride) {
    if (i < 32768) {
      int n = i >> 8, k = i & 255;
      wgs[i] = (f16)((k < 128) ? Wg[k * 128 + n] : Ws[(k - 128) * 128 + n]);
    } else if (i < 98304) {
      int j = i - 32768, c = j >> 7, k = j & 127;
      wt1[j] = (f16)W1[k * 512 + c];
    } else if (i < 360448) {
      int j = i - 98304, c = j >> 9, k = j & 511;
      wt2[j] = (f16)W2[k * 512 + c];
    } else {
      int j = i - 360448, c = j >> 9, k = j & 511;
      wt3[j] = (f16)W3[k * 128 + c];
    }
  }
}

// --------- R5/R11 proven drain GEMM (BK=64, single buffer, swizzled) ----------
template <int K, int NOUT, int WM, int WN, int MI, int ACT, bool OUTF32>
__global__ __launch_bounds__(WM * WN * 64) void gemm_r(
    const f16* __restrict__ X, const f16* __restrict__ Wt,
    const float* __restrict__ bias, void* __restrict__ OutV, int M) {
  constexpr int NJ = 4;
  constexpr int BM = WM * MI * 16;
  constexpr int BN = WN * NJ * 16;
  constexpr int NTHR = WM * WN * 64;
  constexpr int CA = (BM * 128) / (NTHR * 16);
  constexpr int CB = (BN * 128) / (NTHR * 16);
  __shared__ __align__(16) f16 As[BM * 64];
  __shared__ __align__(16) f16 Bs[BN * 64];

  const int tid = threadIdx.x;
  const int wid = tid >> 6, lane = tid & 63;
  const int wm = wid / WN, wn = wid % WN;
  const int lr = lane & 15, lq = lane >> 4;
  const int rxor = lr & 7;
  const long long m0 = (long long)blockIdx.x * BM;
  const int n0 = blockIdx.y * BN;

  const f16* Ag = X + m0 * K;
  const f16* Bg = Wt + (long long)n0 * K;

  long long aOff[CA], bOff[CB];
#pragma unroll
  for (int c = 0; c < CA; ++c) {
    int f = c * NTHR + tid;
    int row = f >> 3, ss = (f & 7) ^ (row & 7);
    aOff[c] = (long long)row * K + ss * 8;
  }
#pragma unroll
  for (int c = 0; c < CB; ++c) {
    int f = c * NTHR + tid;
    int row = f >> 3, ss = (f & 7) ^ (row & 7);
    bOff[c] = (long long)row * K + ss * 8;
  }

  f32x4 acc[MI][NJ];
#pragma unroll
  for (int i = 0; i < MI; ++i)
#pragma unroll
    for (int j = 0; j < NJ; ++j)
#pragma unroll
      for (int r = 0; r < 4; ++r) acc[i][j][r] = 0.0f;

#pragma unroll 1
  for (int k0 = 0; k0 < K; k0 += 64) {
#pragma unroll
    for (int c = 0; c < CA; ++c)
      async_load16(Ag + aOff[c] + k0, (char*)As + c * NTHR * 16 + wid * 1024);
#pragma unroll
    for (int c = 0; c < CB; ++c)
      async_load16(Bg + bOff[c] + k0, (char*)Bs + c * NTHR * 16 + wid * 1024);
    __syncthreads();
#pragma unroll
    for (int kk = 0; kk < 64; kk += 32) {
      const int co = (((kk >> 3) + lq) ^ rxor) * 16;
      f16x8 a[MI], b[NJ];
#pragma unroll
      for (int i = 0; i < MI; ++i)
        a[i] = *reinterpret_cast<const f16x8*>(
            (const char*)As + (wm * MI * 16 + i * 16 + lr) * 128 + co);
#pragma unroll
      for (int j = 0; j < NJ; ++j)
        b[j] = *reinterpret_cast<const f16x8*>(
            (const char*)Bs + (wn * NJ * 16 + j * 16 + lr) * 128 + co);
#pragma unroll
      for (int i = 0; i < MI; ++i)
#pragma unroll
        for (int j = 0; j < NJ; ++j)
          acc[i][j] = __builtin_amdgcn_mfma_f32_16x16x32_f16(a[i], b[j], acc[i][j], 0, 0, 0);
    }
    __syncthreads();
  }

#pragma unroll
  for (int i = 0; i < MI; ++i) {
#pragma unroll
    for (int j = 0; j < NJ; ++j) {
      int col = n0 + wn * NJ * 16 + j * 16 + lr;
      float bv = bias[col];
#pragma unroll
      for (int r = 0; r < 4; ++r) {
        long long row = m0 + wm * MI * 16 + i * 16 + lq * 4 + r;
        if (row < M) {
          float v = acc[i][j][r] + bv;
          if (ACT == 1) v = fmaxf(v, 0.0f);
          else if (ACT == 2) v = fast_tanh(v);
          if constexpr (OUTF32)
            ((float*)OutV)[row * NOUT + col] = v;
          else
            ((f16*)OutV)[row * NOUT + col] = (f16)v;
        }
      }
    }
  }
}

// ------ BK=32 double-buffered prefetch GEMM, SAME 48KB LDS (T3 test) -------
// Wave tile 64x64 (MI=NJ=4); per K-step one MFMA-K slice (32).
// Static named buffers; VMBAR after compute -> prefetch spans the MFMA phase.
// 2-bit swizzle (4 slots/row): source slot ^= row&3, read XORs lr&3.
template <int K, int NOUT, int WM, int WN, int ACT, bool OUTF32>
__global__ __launch_bounds__(WM * WN * 64) void gemm_d(
    const f16* __restrict__ X, const f16* __restrict__ Wt,
    const float* __restrict__ bias, void* __restrict__ OutV, int M) {
  constexpr int BM = WM * 64;
  constexpr int BN = WN * 64;
  constexpr int NTHR = WM * WN * 64;
  constexpr int CA = (BM * 4) / NTHR;  // 16B units per thread (A)
  constexpr int CB = (BN * 4) / NTHR;
  constexpr int NT = K / 32;           // even for K in {128, 512}
  __shared__ __align__(16) f16 A0[BM * 32], A1[BM * 32];
  __shared__ __align__(16) f16 B0[BN * 32], B1[BN * 32];

  const int tid = threadIdx.x;
  const int wid = tid >> 6, lane = tid & 63;
  const int wm = wid / WN, wn = wid % WN;
  const int lr = lane & 15, lq = lane >> 4;
  const long long m0 = (long long)blockIdx.x * BM;
  const int n0 = blockIdx.y * BN;

  const f16* Ag = X + m0 * K;
  const f16* Bg = Wt + (long long)n0 * K;

  long long aOff[CA], bOff[CB];
#pragma unroll
  for (int c = 0; c < CA; ++c) {
    int f = c * NTHR + tid;
    int row = f >> 2, ss = (f & 3) ^ (row & 3);
    aOff[c] = (long long)row * K + ss * 8;
  }
#pragma unroll
  for (int c = 0; c < CB; ++c) {
    int f = c * NTHR + tid;
    int row = f >> 2, ss = (f & 3) ^ (row & 3);
    bOff[c] = (long long)row * K + ss * 8;
  }

  f32x4 acc[4][4];
#pragma unroll
  for (int i = 0; i < 4; ++i)
#pragma unroll
    for (int j = 0; j < 4; ++j)
#pragma unroll
      for (int r = 0; r < 4; ++r) acc[i][j][r] = 0.0f;

  auto STAGE = [&](f16* dA, f16* dB, int k0) {
#pragma unroll
    for (int c = 0; c < CA; ++c)
      async_load16(Ag + aOff[c] + k0, (char*)dA + (c * NTHR + wid * 64) * 16);
#pragma unroll
    for (int c = 0; c < CB; ++c)
      async_load16(Bg + bOff[c] + k0, (char*)dB + (c * NTHR + wid * 64) * 16);
  };

  const int co = ((lq ^ (lr & 3)) * 16);  // swizzled byte col within 64B row
  auto COMPUTE = [&](const f16* sA, const f16* sB) {
    f16x8 a[4], b[4];
#pragma unroll
    for (int i = 0; i < 4; ++i)
      a[i] = *reinterpret_cast<const f16x8*>(
          (const char*)sA + (wm * 64 + i * 16 + lr) * 64 + co);
#pragma unroll
    for (int j = 0; j < 4; ++j)
      b[j] = *reinterpret_cast<const f16x8*>(
          (const char*)sB + (wn * 64 + j * 16 + lr) * 64 + co);
#pragma unroll
    for (int i = 0; i < 4; ++i)
#pragma unroll
      for (int j = 0; j < 4; ++j)
        acc[i][j] = __builtin_amdgcn_mfma_f32_16x16x32_f16(a[i], b[j], acc[i][j], 0, 0, 0);
  };

  STAGE(A0, B0, 0);
  VMBAR();
#pragma unroll 1
  for (int t = 0; t < NT; t += 2) {
    STAGE(A1, B1, (t + 1) * 32);   // prefetch next slice during compute
    COMPUTE(A0, B0);
    VMBAR();
    if (t + 2 < NT) STAGE(A0, B0, (t + 2) * 32);
    COMPUTE(A1, B1);
    if (t + 2 < NT) VMBAR();
  }

#pragma unroll
  for (int i = 0; i < 4; ++i) {
#pragma unroll
    for (int j = 0; j < 4; ++j) {
      int col = n0 + wn * 64 + j * 16 + lr;
      float bv = bias[col];
#pragma unroll
      for (int r = 0; r < 4; ++r) {
        long long row = m0 + wm * 64 + i * 16 + lq * 4 + r;
        if (row < M) {
          float v = acc[i][j][r] + bv;
          if (ACT == 1) v = fmaxf(v, 0.0f);
          else if (ACT == 2) v = fast_tanh(v);
          if constexpr (OUTF32)
            ((float*)OutV)[row * NOUT + col] = v;
          else
            ((f16*)OutV)[row * NOUT + col] = (f16)v;
        }
      }
    }
  }
}

extern "C" void kernel_launch(void* const* d_in, const int* in_sizes, int n_in,
                              void* d_out, int out_size, void* d_ws, size_t ws_size,
                              hipStream_t stream) {
  const float* z  = (const float*)d_in[0];
  const int*   ei = (const int*)d_in[1];
  const float* Wg = (const float*)d_in[2];
  const float* Ws = (const float*)d_in[3];
  const float* bg = (const float*)d_in[4];
  const float* W1 = (const float*)d_in[5];
  const float* b1 = (const float*)d_in[6];
  const float* W2 = (const float*)d_in[7];
  const float* b2 = (const float*)d_in[8];
  const float* W3 = (const float*)d_in[9];
  const float* b3 = (const float*)d_in[10];

  const int Nn = in_sizes[0] / 128;
  const int E  = in_sizes[1] / 2;
  const int* src = ei;
  const int* dst = ei + E;
  const int nb = (Nn + 1023) / 1024;
  const int gm128 = (Nn + 127) / 128;
  const long long Mpad = (long long)gm128 * 128;

  // workspace overlay (peak ~207 MB):
  //   [0, 51.2M)        Xc    (cast/gather -> gemm1)
  //   [51.2, 76.8M)     h1    (gemm1 -> gemm2)
  //   [76.8, ~106M)     CSR + z16 (dead after gather)
  //   [0, 102.4M)       h3    (gemm3 -> gemm4; overlays Xc,h1,CSR head)
  //   [102.4, 204.8M)   h2    (gemm2 -> gemm3)
  //   [204.8M, ...)     prepped weights (~1.7 MB)
  char* base = (char*)d_ws;
  const size_t XCB = (size_t)Mpad * 256 * 2;
  const size_t H1B = (size_t)Mpad * 128 * 2;
  const size_t H3B = (size_t)Mpad * 512 * 2;
  f16* Xc = (f16*)(base);
  f16* h1 = (f16*)(base + XCB);
  f16* h3 = (f16*)(base);
  size_t off = XCB + H1B;
  auto alloc = [&](size_t b) -> void* {
    void* p = base + off;
    off += (b + 255) & ~(size_t)255;
    return p;
  };
  int* degi      = (int*)alloc((size_t)Nn * 4);
  int* row_start = (int*)alloc((size_t)(Nn + 1) * 4);
  int* cursor    = (int*)alloc((size_t)Nn * 4);
  int* adj       = (int*)alloc((size_t)(E + 8) * 4);  // +8 pad for masked batch
  int* bsum      = (int*)alloc((size_t)nb * 4);
  int* boff      = (int*)alloc((size_t)nb * 4);
  f16* z16       = (f16*)alloc((size_t)Nn * 128 * 2);
  off = H3B;
  f16* h2  = (f16*)alloc((size_t)Mpad * 512 * 2);
  f16* wgs = (f16*)alloc((size_t)128 * 256 * 2);
  f16* wt1 = (f16*)alloc((size_t)512 * 128 * 2);
  f16* wt2 = (f16*)alloc((size_t)512 * 512 * 2);
  f16* wt3 = (f16*)alloc((size_t)128 * 512 * 2);

  // CSR build
  zero_kernel<<<(Nn + 255) / 256, 256, 0, stream>>>(degi, Nn);
  deg_count<<<(E + 255) / 256, 256, 0, stream>>>(dst, degi, E);
  scan_partial<<<nb, 256, 0, stream>>>(degi, bsum, Nn);
  scan_bsums<<<1, 64, 0, stream>>>(bsum, boff, row_start, nb, Nn);
  scan_final<<<nb, 256, 0, stream>>>(degi, boff, row_start, cursor, Nn);
  fill_adj<<<(E + 255) / 256, 256, 0, stream>>>(src, dst, cursor, adj, E);

  // weight prep + z16 cast (also fills Xc z-half)
  prep_weights<<<416, 256, 0, stream>>>(Wg, Ws, W1, W2, W3, wgs, wt1, wt2, wt3);
  cast_z16<<<2048, 256, 0, stream>>>(z, z16, Xc, Nn * 32);

  // gather mean-half
  {
    long long tot = (long long)Nn * 32;
    gather_xcat<<<(int)((tot + 255) / 256), 256, 0, stream>>>(z16, row_start, adj, Xc, Nn);
  }

  // GEMMs: L1/L4 on proven gemm_r; L2/L3 on BK=32 dbuf gemm_d (T3 A/B test).
  gemm_r<256, 128, 2, 2, 4, 1, false><<<dim3(gm128, 1), 256, 0, stream>>>(Xc, wgs, bg, (void*)h1, Nn);
  gemm_d<128, 512, 2, 4, 2, false><<<dim3(gm128, 2), 512, 0, stream>>>(h1, wt1, b1, (void*)h2, Nn);
  gemm_d<512, 512, 2, 4, 2, false><<<dim3(gm128, 2), 512, 0, stream>>>(h2, wt2, b2, (void*)h3, Nn);
  gemm_r<512, 128, 2, 2, 4, 0, true><<<dim3(gm128, 1), 256, 0, stream>>>(h3, wt3, b3, d_out, Nn);
}

// Round 13
// 329.075 us; speedup vs baseline: 1.0472x; 1.0472x over previous
//
#include <hip/hip_runtime.h>
#include <hip/hip_fp16.h>

// GDE func: out = MLP(relu(mean_agg(z,edges)@Wg + z@Ws + bg))
// Round 12 -> 13: consolidation. (1) L2/L3 revert to proven gemm_r drain
// schedule (gemm_d BK=32 dbuf lost 12% + brought back bank conflicts).
// (2) keep R12's masked-8 gather + cast-z-half (saved ~13us). (3) merge
// deg_count + prep_weights + cast_z16 into one grid-stride kernel.

typedef _Float16 f16;
typedef __attribute__((ext_vector_type(4))) _Float16 f16x4;
typedef __attribute__((ext_vector_type(8))) _Float16 f16x8;
typedef __attribute__((ext_vector_type(4))) float f32x4;

__device__ __forceinline__ void async_load16(const void* g, void* lds) {
  __builtin_amdgcn_global_load_lds(
      (const __attribute__((address_space(1))) void*)g,
      (__attribute__((address_space(3))) void*)lds, 16, 0, 0);
}

__device__ __forceinline__ float fast_tanh(float x) {
  float a = fabsf(x);
  float e = __expf(-2.0f * a);
  float r = (1.0f - e) * __builtin_amdgcn_rcpf(1.0f + e);
  return copysignf(r, x);
}

__global__ __launch_bounds__(256) void zero_kernel(int* __restrict__ p, int n) {
  int i = blockIdx.x * 256 + threadIdx.x;
  int stride = gridDim.x * 256;
  for (; i < n; i += stride) p[i] = 0;
}

// ---- CSR scan ----
__global__ __launch_bounds__(256) void scan_partial(const int* __restrict__ degi,
                                                    int* __restrict__ bsum, int N) {
  __shared__ int lds[256];
  int b = blockIdx.x, t = threadIdx.x;
  int s = 0;
#pragma unroll
  for (int j = 0; j < 4; ++j) {
    int idx = b * 1024 + t * 4 + j;
    if (idx < N) s += degi[idx];
  }
  lds[t] = s;
  __syncthreads();
  for (int off = 128; off > 0; off >>= 1) {
    if (t < off) lds[t] += lds[t + off];
    __syncthreads();
  }
  if (t == 0) bsum[b] = lds[0];
}

__global__ void scan_bsums(const int* __restrict__ bsum, int* __restrict__ boff,
                           int* __restrict__ row_start, int nb, int N) {
  if (threadIdx.x == 0 && blockIdx.x == 0) {
    int acc = 0;
    for (int i = 0; i < nb; ++i) { boff[i] = acc; acc += bsum[i]; }
    row_start[N] = acc;  // == E
  }
}

__global__ __launch_bounds__(256) void scan_final(
    const int* __restrict__ degi, const int* __restrict__ boff,
    int* __restrict__ row_start, int* __restrict__ cursor, int N) {
  __shared__ int lds[256];
  int b = blockIdx.x, t = threadIdx.x;
  int base = b * 1024;
  int v[4];
  int s = 0;
#pragma unroll
  for (int j = 0; j < 4; ++j) {
    int idx = base + t * 4 + j;
    v[j] = (idx < N) ? degi[idx] : 0;
    s += v[j];
  }
  lds[t] = s;
  __syncthreads();
  for (int off = 1; off < 256; off <<= 1) {
    int x = lds[t];
    int y = (t >= off) ? lds[t - off] : 0;
    __syncthreads();
    lds[t] = x + y;
    __syncthreads();
  }
  int pre = boff[b] + lds[t] - s;
#pragma unroll
  for (int j = 0; j < 4; ++j) {
    int idx = base + t * 4 + j;
    if (idx < N) { row_start[idx] = pre; cursor[idx] = pre; pre += v[j]; }
  }
}

__global__ __launch_bounds__(256) void fill_adj(const int* __restrict__ src,
                                                const int* __restrict__ dst,
                                                int* __restrict__ cursor,
                                                int* __restrict__ adj, int E) {
  int e = blockIdx.x * 256 + threadIdx.x;
  if (e >= E) return;
  int p = atomicAdd(&cursor[dst[e]], 1);
  adj[p] = src[e];
}

// ---- merged: deg_count + weight prep + z16 cast (+Xc z-half) ----
// independent tasks share one grid-stride dispatch for launch/overlap savings.
__global__ __launch_bounds__(256) void fused_prep(
    const int* __restrict__ dst, int* __restrict__ degi, int E,
    const float* __restrict__ Wg, const float* __restrict__ Ws,
    const float* __restrict__ W1, const float* __restrict__ W2,
    const float* __restrict__ W3, f16* __restrict__ wgs, f16* __restrict__ wt1,
    f16* __restrict__ wt2, f16* __restrict__ wt3,
    const float* __restrict__ z, f16* __restrict__ z16, f16* __restrict__ Xc,
    int n4) {
  int i0 = blockIdx.x * 256 + threadIdx.x;
  int stride = gridDim.x * 256;
  for (int i = i0; i < n4; i += stride) {
    float4 v = *(const float4*)(z + 4 * (long long)i);
    f16x4 c;
    c[0] = (f16)v.x; c[1] = (f16)v.y; c[2] = (f16)v.z; c[3] = (f16)v.w;
    *(f16x4*)(z16 + 4 * (long long)i) = c;
    int node = i >> 5, sl = i & 31;
    *(f16x4*)(Xc + (long long)node * 256 + 128 + 4 * sl) = c;
  }
  for (int i = i0; i < E; i += stride) atomicAdd(&degi[dst[i]], 1);
  for (int i = i0; i < 425984; i += stride) {
    if (i < 32768) {
      int n = i >> 8, k = i & 255;
      wgs[i] = (f16)((k < 128) ? Wg[k * 128 + n] : Ws[(k - 128) * 128 + n]);
    } else if (i < 98304) {
      int j = i - 32768, c = j >> 7, k = j & 127;
      wt1[j] = (f16)W1[k * 512 + c];
    } else if (i < 360448) {
      int j = i - 98304, c = j >> 9, k = j & 511;
      wt2[j] = (f16)W2[k * 512 + c];
    } else {
      int j = i - 360448, c = j >> 9, k = j & 511;
      wt3[j] = (f16)W3[k * 128 + c];
    }
  }
}

// ---- gather + mean -> Xc mean-half: 32 lanes/node, masked 8-wide batch ----
__global__ __launch_bounds__(256) void gather_xcat(
    const f16* __restrict__ z16, const int* __restrict__ row_start,
    const int* __restrict__ adj, f16* __restrict__ Xc, int N) {
  int node = (blockIdx.x * 256 + threadIdx.x) >> 5;
  if (node >= N) return;
  int lane = threadIdx.x & 31;
  int beg = row_start[node], end = row_start[node + 1];
  float a0 = 0, a1 = 0, a2 = 0, a3 = 0;
#pragma unroll
  for (int j = 0; j < 8; ++j) {
    int idx = beg + j;
    bool vld = idx < end;
    int nb = vld ? adj[idx] : node;
    f16x4 x = *(const f16x4*)(z16 + (long long)nb * 128 + 4 * lane);
    float w = vld ? 1.0f : 0.0f;
    a0 += w * (float)x[0]; a1 += w * (float)x[1];
    a2 += w * (float)x[2]; a3 += w * (float)x[3];
  }
  int i = beg + 8;
  if (i < end) {
    float b0 = 0, b1 = 0, b2 = 0, b3 = 0;
    float c0 = 0, c1 = 0, c2 = 0, c3 = 0;
    float d0 = 0, d1 = 0, d2 = 0, d3 = 0;
    for (; i + 4 <= end; i += 4) {
      int n0 = adj[i], n1 = adj[i + 1], n2 = adj[i + 2], n3 = adj[i + 3];
      f16x4 v0 = *(const f16x4*)(z16 + (long long)n0 * 128 + 4 * lane);
      f16x4 v1 = *(const f16x4*)(z16 + (long long)n1 * 128 + 4 * lane);
      f16x4 v2 = *(const f16x4*)(z16 + (long long)n2 * 128 + 4 * lane);
      f16x4 v3 = *(const f16x4*)(z16 + (long long)n3 * 128 + 4 * lane);
      a0 += (float)v0[0]; a1 += (float)v0[1]; a2 += (float)v0[2]; a3 += (float)v0[3];
      b0 += (float)v1[0]; b1 += (float)v1[1]; b2 += (float)v1[2]; b3 += (float)v1[3];
      c0 += (float)v2[0]; c1 += (float)v2[1]; c2 += (float)v2[2]; c3 += (float)v2[3];
      d0 += (float)v3[0]; d1 += (float)v3[1]; d2 += (float)v3[2]; d3 += (float)v3[3];
    }
    for (; i < end; ++i) {
      f16x4 v = *(const f16x4*)(z16 + (long long)adj[i] * 128 + 4 * lane);
      a0 += (float)v[0]; a1 += (float)v[1]; a2 += (float)v[2]; a3 += (float)v[3];
    }
    a0 += b0 + c0 + d0; a1 += b1 + c1 + d1;
    a2 += b2 + c2 + d2; a3 += b3 + c3 + d3;
  }
  int dg = end - beg;
  float inv = 1.0f / (float)(dg > 1 ? dg : 1);
  long long o = (long long)node * 256;
  f16x4 m;
  m[0] = (f16)(a0 * inv); m[1] = (f16)(a1 * inv);
  m[2] = (f16)(a2 * inv); m[3] = (f16)(a3 * inv);
  *(f16x4*)(Xc + o + 4 * lane) = m;
}

// --------- R5/R11 proven drain GEMM (BK=64, single buffer, swizzled) ----------
template <int K, int NOUT, int WM, int WN, int MI, int ACT, bool OUTF32>
__global__ __launch_bounds__(WM * WN * 64) void gemm_r(
    const f16* __restrict__ X, const f16* __restrict__ Wt,
    const float* __restrict__ bias, void* __restrict__ OutV, int M) {
  constexpr int NJ = 4;
  constexpr int BM = WM * MI * 16;
  constexpr int BN = WN * NJ * 16;
  constexpr int NTHR = WM * WN * 64;
  constexpr int CA = (BM * 128) / (NTHR * 16);
  constexpr int CB = (BN * 128) / (NTHR * 16);
  __shared__ __align__(16) f16 As[BM * 64];
  __shared__ __align__(16) f16 Bs[BN * 64];

  const int tid = threadIdx.x;
  const int wid = tid >> 6, lane = tid & 63;
  const int wm = wid / WN, wn = wid % WN;
  const int lr = lane & 15, lq = lane >> 4;
  const int rxor = lr & 7;
  const long long m0 = (long long)blockIdx.x * BM;
  const int n0 = blockIdx.y * BN;

  const f16* Ag = X + m0 * K;
  const f16* Bg = Wt + (long long)n0 * K;

  long long aOff[CA], bOff[CB];
#pragma unroll
  for (int c = 0; c < CA; ++c) {
    int f = c * NTHR + tid;
    int row = f >> 3, ss = (f & 7) ^ (row & 7);
    aOff[c] = (long long)row * K + ss * 8;
  }
#pragma unroll
  for (int c = 0; c < CB; ++c) {
    int f = c * NTHR + tid;
    int row = f >> 3, ss = (f & 7) ^ (row & 7);
    bOff[c] = (long long)row * K + ss * 8;
  }

  f32x4 acc[MI][NJ];
#pragma unroll
  for (int i = 0; i < MI; ++i)
#pragma unroll
    for (int j = 0; j < NJ; ++j)
#pragma unroll
      for (int r = 0; r < 4; ++r) acc[i][j][r] = 0.0f;

#pragma unroll 1
  for (int k0 = 0; k0 < K; k0 += 64) {
#pragma unroll
    for (int c = 0; c < CA; ++c)
      async_load16(Ag + aOff[c] + k0, (char*)As + c * NTHR * 16 + wid * 1024);
#pragma unroll
    for (int c = 0; c < CB; ++c)
      async_load16(Bg + bOff[c] + k0, (char*)Bs + c * NTHR * 16 + wid * 1024);
    __syncthreads();
#pragma unroll
    for (int kk = 0; kk < 64; kk += 32) {
      const int co = (((kk >> 3) + lq) ^ rxor) * 16;
      f16x8 a[MI], b[NJ];
#pragma unroll
      for (int i = 0; i < MI; ++i)
        a[i] = *reinterpret_cast<const f16x8*>(
            (const char*)As + (wm * MI * 16 + i * 16 + lr) * 128 + co);
#pragma unroll
      for (int j = 0; j < NJ; ++j)
        b[j] = *reinterpret_cast<const f16x8*>(
            (const char*)Bs + (wn * NJ * 16 + j * 16 + lr) * 128 + co);
#pragma unroll
      for (int i = 0; i < MI; ++i)
#pragma unroll
        for (int j = 0; j < NJ; ++j)
          acc[i][j] = __builtin_amdgcn_mfma_f32_16x16x32_f16(a[i], b[j], acc[i][j], 0, 0, 0);
    }
    __syncthreads();
  }

#pragma unroll
  for (int i = 0; i < MI; ++i) {
#pragma unroll
    for (int j = 0; j < NJ; ++j) {
      int col = n0 + wn * NJ * 16 + j * 16 + lr;
      float bv = bias[col];
#pragma unroll
      for (int r = 0; r < 4; ++r) {
        long long row = m0 + wm * MI * 16 + i * 16 + lq * 4 + r;
        if (row < M) {
          float v = acc[i][j][r] + bv;
          if (ACT == 1) v = fmaxf(v, 0.0f);
          else if (ACT == 2) v = fast_tanh(v);
          if constexpr (OUTF32)
            ((float*)OutV)[row * NOUT + col] = v;
          else
            ((f16*)OutV)[row * NOUT + col] = (f16)v;
        }
      }
    }
  }
}

extern "C" void kernel_launch(void* const* d_in, const int* in_sizes, int n_in,
                              void* d_out, int out_size, void* d_ws, size_t ws_size,
                              hipStream_t stream) {
  const float* z  = (const float*)d_in[0];
  const int*   ei = (const int*)d_in[1];
  const float* Wg = (const float*)d_in[2];
  const float* Ws = (const float*)d_in[3];
  const float* bg = (const float*)d_in[4];
  const float* W1 = (const float*)d_in[5];
  const float* b1 = (const float*)d_in[6];
  const float* W2 = (const float*)d_in[7];
  const float* b2 = (const float*)d_in[8];
  const float* W3 = (const float*)d_in[9];
  const float* b3 = (const float*)d_in[10];

  const int Nn = in_sizes[0] / 128;
  const int E  = in_sizes[1] / 2;
  const int* src = ei;
  const int* dst = ei + E;
  const int nb = (Nn + 1023) / 1024;
  const int gm128 = (Nn + 127) / 128;
  const long long Mpad = (long long)gm128 * 128;

  // workspace overlay (peak ~207 MB):
  //   [0, 51.2M)        Xc    (prep/gather -> gemm1)
  //   [51.2, 76.8M)     h1    (gemm1 -> gemm2)
  //   [76.8, ~106M)     CSR + z16 (dead after gather)
  //   [0, 102.4M)       h3    (gemm3 -> gemm4; overlays Xc,h1,CSR head)
  //   [102.4, 204.8M)   h2    (gemm2 -> gemm3)
  //   [204.8M, ...)     prepped weights (~1.7 MB)
  char* base = (char*)d_ws;
  const size_t XCB = (size_t)Mpad * 256 * 2;
  const size_t H1B = (size_t)Mpad * 128 * 2;
  const size_t H3B = (size_t)Mpad * 512 * 2;
  f16* Xc = (f16*)(base);
  f16* h1 = (f16*)(base + XCB);
  f16* h3 = (f16*)(base);
  size_t off = XCB + H1B;
  auto alloc = [&](size_t b) -> void* {
    void* p = base + off;
    off += (b + 255) & ~(size_t)255;
    return p;
  };
  int* degi      = (int*)alloc((size_t)Nn * 4);
  int* row_start = (int*)alloc((size_t)(Nn + 1) * 4);
  int* cursor    = (int*)alloc((size_t)Nn * 4);
  int* adj       = (int*)alloc((size_t)(E + 8) * 4);  // +8 pad for masked batch
  int* bsum      = (int*)alloc((size_t)nb * 4);
  int* boff      = (int*)alloc((size_t)nb * 4);
  f16* z16       = (f16*)alloc((size_t)Nn * 128 * 2);
  off = H3B;
  f16* h2  = (f16*)alloc((size_t)Mpad * 512 * 2);
  f16* wgs = (f16*)alloc((size_t)128 * 256 * 2);
  f16* wt1 = (f16*)alloc((size_t)512 * 128 * 2);
  f16* wt2 = (f16*)alloc((size_t)512 * 512 * 2);
  f16* wt3 = (f16*)alloc((size_t)128 * 512 * 2);

  // CSR + prep
  zero_kernel<<<(Nn + 255) / 256, 256, 0, stream>>>(degi, Nn);
  fused_prep<<<2048, 256, 0, stream>>>(dst, degi, E, Wg, Ws, W1, W2, W3,
                                       wgs, wt1, wt2, wt3, z, z16, Xc, Nn * 32);
  scan_partial<<<nb, 256, 0, stream>>>(degi, bsum, Nn);
  scan_bsums<<<1, 64, 0, stream>>>(bsum, boff, row_start, nb, Nn);
  scan_final<<<nb, 256, 0, stream>>>(degi, boff, row_start, cursor, Nn);
  fill_adj<<<(E + 255) / 256, 256, 0, stream>>>(src, dst, cursor, adj, E);

  // gather mean-half
  {
    long long tot = (long long)Nn * 32;
    gather_xcat<<<(int)((tot + 255) / 256), 256, 0, stream>>>(z16, row_start, adj, Xc, Nn);
  }

  // GEMMs: all on proven gemm_r (R11 config).
  gemm_r<256, 128, 2, 2, 4, 1, false><<<dim3(gm128, 1), 256, 0, stream>>>(Xc, wgs, bg, (void*)h1, Nn);
  gemm_r<128, 512, 2, 4, 4, 2, false><<<dim3(gm128, 2), 512, 0, stream>>>(h1, wt1, b1, (void*)h2, Nn);
  gemm_r<512, 512, 2, 4, 4, 2, false><<<dim3(gm128, 2), 512, 0, stream>>>(h2, wt2, b2, (void*)h3, Nn);
  gemm_r<512, 128, 2, 2, 4, 0, true><<<dim3(gm128, 1), 256, 0, stream>>>(h3, wt3, b3, d_out, Nn);
}